// Round 2
// baseline (2909.495 us; speedup 1.0000x reference)
//
#include <hip/hip_runtime.h>

#define N_NODES 100000
#define N_EDGES 3200000
#define D 128

#define K1C    782        // coarse buckets: bucket = dst >> 7 (128 nodes each)
#define CHUNK  6144       // edges per partition block
#define NCHUNK 521        // ceil(N_EDGES / CHUNK)
#define APAD   132        // acc row stride in dwords (pad breaks bank aliasing)

// ---------------------------------------------------------------------------
// Workspace layout (bytes). Total ~77.3 MB; ws >= 78,000,512 proven round 2.
// ---------------------------------------------------------------------------
static const size_t OFF_SB    = 0;           // S bf16 packed: N*64 uints = 25.6 MB
static const size_t OFF_REC   = 25600000;    // E int2 (coarse-partitioned)
static const size_t OFF_GHIST = 77200000;
static const size_t OFF_BOFFS = 77204096;
static const size_t OFF_GCUR  = 77208192;

typedef __attribute__((ext_vector_type(8))) short bf16x8;
typedef __attribute__((ext_vector_type(4))) float f32x4;

__device__ __forceinline__ unsigned short f2bf(float f) {
    unsigned u = __float_as_uint(f);
    return (unsigned short)((u + 0x7FFFu + ((u >> 16) & 1u)) >> 16);   // RNE
}

// ---------------------------------------------------------------------------
// S = X @ W via MFMA — verified in round 5 (absmax matched VALU-bf16 path).
// ---------------------------------------------------------------------------
__global__ __launch_bounds__(256) void gemm_mfma(const float* __restrict__ X,
                                                 const float* __restrict__ W,
                                                 unsigned* __restrict__ Sb) {
    __shared__ __align__(16) union {
        unsigned short wfrag[8][4][64][8];  // [ct][kt][lane][j] = 32 KB
        unsigned       stage[4][32][68];    // [wave][row][dword] = 34 KB
    } u;

    const int t    = threadIdx.x;
    const int lane = t & 63;
    const int wave = t >> 6;
    const int quad = lane >> 4;
    const int li   = lane & 15;
    const int rowBase = blockIdx.x * 128;

    // stage W[k][n] fp32 -> pre-packed bf16 B-fragments
    for (int i = t; i < D * D; i += 256) {
        int k = i >> 7, n = i & 127;
        u.wfrag[n >> 4][k >> 5][((k >> 3) & 3) * 16 + (n & 15)][k & 7] = f2bf(W[i]);
    }
    __syncthreads();

    f32x4 acc[2][8];
#pragma unroll
    for (int rt = 0; rt < 2; ++rt)
#pragma unroll
        for (int ct = 0; ct < 8; ++ct)
            acc[rt][ct] = (f32x4){0.f, 0.f, 0.f, 0.f};

#pragma unroll
    for (int kt = 0; kt < 4; ++kt) {
        bf16x8 a[2];
#pragma unroll
        for (int rt = 0; rt < 2; ++rt) {
            int row = rowBase + wave * 32 + rt * 16 + li;
            if (row >= N_NODES) row = N_NODES - 1;           // clamp; store masked
            const float* xp = X + (size_t)row * D + kt * 32 + quad * 8;
            float4 f0 = ((const float4*)xp)[0];
            float4 f1 = ((const float4*)xp)[1];
            bf16x8 av;
            av[0] = (short)f2bf(f0.x); av[1] = (short)f2bf(f0.y);
            av[2] = (short)f2bf(f0.z); av[3] = (short)f2bf(f0.w);
            av[4] = (short)f2bf(f1.x); av[5] = (short)f2bf(f1.y);
            av[6] = (short)f2bf(f1.z); av[7] = (short)f2bf(f1.w);
            a[rt] = av;
        }
#pragma unroll
        for (int ct = 0; ct < 8; ++ct) {
            bf16x8 b = *(const bf16x8*)&u.wfrag[ct][kt][lane][0];
            acc[0][ct] = __builtin_amdgcn_mfma_f32_16x16x32_bf16(a[0], b, acc[0][ct], 0, 0, 0);
            acc[1][ct] = __builtin_amdgcn_mfma_f32_16x16x32_bf16(a[1], b, acc[1][ct], 0, 0, 0);
        }
    }
    __syncthreads();

    unsigned short* sw = (unsigned short*)&u.stage[wave][0][0];  // 32 x 136 bf16
#pragma unroll
    for (int rt = 0; rt < 2; ++rt)
#pragma unroll
        for (int r = 0; r < 4; ++r) {
            int lrow = rt * 16 + quad * 4 + r;
#pragma unroll
            for (int ct = 0; ct < 8; ++ct)
                sw[lrow * 136 + ct * 16 + li] = f2bf(acc[rt][ct][r]);
        }
    for (int lrow = 0; lrow < 32; ++lrow) {
        int node = rowBase + wave * 32 + lrow;
        if (node < N_NODES)
            Sb[(size_t)node * 64 + lane] = ((unsigned*)sw)[lrow * 68 + lane];
    }
}

// ---------------------------------------------------------------------------
// Coarse histogram over K1C buckets (bucket = dst >> 7)
// ---------------------------------------------------------------------------
__global__ __launch_bounds__(256) void hist_coarse(const int* __restrict__ edst,
                                                   int* __restrict__ ghist) {
    __shared__ int h[K1C];
    for (int i = threadIdx.x; i < K1C; i += 256) h[i] = 0;
    __syncthreads();
    for (int e = blockIdx.x * 256 + threadIdx.x; e < N_EDGES; e += gridDim.x * 256)
        atomicAdd(&h[edst[e] >> 7], 1);
    __syncthreads();
    for (int i = threadIdx.x; i < K1C; i += 256)
        if (h[i]) atomicAdd(&ghist[i], h[i]);
}

__global__ __launch_bounds__(256) void scan_coarse(const int* __restrict__ ghist,
                                                   int* __restrict__ boffs,
                                                   int* __restrict__ gcursor) {
    __shared__ int sc[256];
    const int t = threadIdx.x;
    int v[4]; int s = 0;
#pragma unroll
    for (int j = 0; j < 4; ++j) {
        int idx = t * 4 + j;
        v[j] = (idx < K1C) ? ghist[idx] : 0;
        s += v[j];
    }
    sc[t] = s;
    __syncthreads();
    for (int off = 1; off < 256; off <<= 1) {
        int u = (t >= off) ? sc[t - off] : 0;
        __syncthreads();
        sc[t] += u;
        __syncthreads();
    }
    int run = (t == 0) ? 0 : sc[t - 1];
#pragma unroll
    for (int j = 0; j < 4; ++j) {
        int idx = t * 4 + j;
        if (idx < K1C) { boffs[idx] = run; gcursor[idx] = run; }
        run += v[j];
    }
    if (t == 255) boffs[K1C] = run;
}

// ---------------------------------------------------------------------------
// LDS-staged coarse partition, two-pass-per-block (hist then re-read+scatter).
// rec.x = src | (dst&127)<<17 ; rec.y = val bits.
// ---------------------------------------------------------------------------
__global__ __launch_bounds__(512) void partition_edges(
        const int* __restrict__ esrc,
        const int* __restrict__ edst,
        const float* __restrict__ eval,
        int* __restrict__ gcursor,
        int2* __restrict__ rec_out) {
    __shared__ int  hist[K1C];
    __shared__ int  lofs[K1C];
    __shared__ int  gbase[K1C];
    __shared__ int  cur[K1C];
    __shared__ int  sc[512];
    __shared__ int2 staged[CHUNK];
    __shared__ unsigned short bkt[CHUNK];

    const int t   = threadIdx.x;
    const int e0  = blockIdx.x * CHUNK;
    const int cnt = min(CHUNK, N_EDGES - e0);

    for (int i = t; i < K1C; i += 512) hist[i] = 0;
    __syncthreads();

    // pass 1: block-local histogram (edst read is coalesced; re-read below is L2-hot)
    for (int i = t; i < cnt; i += 512)
        atomicAdd(&hist[edst[e0 + i] >> 7], 1);
    __syncthreads();

    // block scan: two buckets per thread (K1C=782 <= 1024)
    int i0 = t * 2, i1 = t * 2 + 1;
    int hv0 = (i0 < K1C) ? hist[i0] : 0;
    int hv1 = (i1 < K1C) ? hist[i1] : 0;
    sc[t] = hv0 + hv1;
    __syncthreads();
    for (int off = 1; off < 512; off <<= 1) {
        int u = (t >= off) ? sc[t - off] : 0;
        __syncthreads();
        sc[t] += u;
        __syncthreads();
    }
    {
        int excl = sc[t] - (hv0 + hv1);
        if (i0 < K1C) {
            lofs[i0]  = excl;
            cur[i0]   = excl;
            gbase[i0] = hv0 ? atomicAdd(&gcursor[i0], hv0) : 0;
        }
        if (i1 < K1C) {
            lofs[i1]  = excl + hv0;
            cur[i1]   = excl + hv0;
            gbase[i1] = hv1 ? atomicAdd(&gcursor[i1], hv1) : 0;
        }
    }
    __syncthreads();

    // pass 2: re-read edges, scatter into LDS staging (bucket-sorted)
    for (int i = t; i < cnt; i += 512) {
        int e = e0 + i;
        int d = edst[e];
        int b = d >> 7;
        int pos = atomicAdd(&cur[b], 1);
        staged[pos] = make_int2(esrc[e] | ((d & 127) << 17), __float_as_int(eval[e]));
        bkt[pos] = (unsigned short)b;
    }
    __syncthreads();

    // writeout: contiguous per-bucket runs
    for (int i = t; i < cnt; i += 512) {
        int bb = bkt[i];
        rec_out[gbase[bb] + (i - lofs[bb])] = staged[i];
    }
}

// ---------------------------------------------------------------------------
// Bucket-level gather + LDS-atomic accumulate (replaces fine_sort + per-node
// reduce). One block per 128-node dst bucket; 66 KB f32 acc tile in LDS.
// Records consumed unsorted: group-of-4 uint4 gathers (4 rows / 1 KB per
// instr), val*bf16 products atomically added to acc rows via ds_add_f32.
// Padded-lane records are (0,0): val=0, src=0 -> harmless zero adds.
// ---------------------------------------------------------------------------
#define ACC8(sx, v, p) {                                                     \
    float* ap = acc + ((unsigned)(sx) >> 17 & 127) * APAD + ql * 8;          \
    atomicAdd(ap + 0, (v) * __uint_as_float((p).x << 16));                   \
    atomicAdd(ap + 1, (v) * __uint_as_float((p).x & 0xFFFF0000u));           \
    atomicAdd(ap + 2, (v) * __uint_as_float((p).y << 16));                   \
    atomicAdd(ap + 3, (v) * __uint_as_float((p).y & 0xFFFF0000u));           \
    atomicAdd(ap + 4, (v) * __uint_as_float((p).z << 16));                   \
    atomicAdd(ap + 5, (v) * __uint_as_float((p).z & 0xFFFF0000u));           \
    atomicAdd(ap + 6, (v) * __uint_as_float((p).w << 16));                   \
    atomicAdd(ap + 7, (v) * __uint_as_float((p).w & 0xFFFF0000u));           \
}

__global__ __launch_bounds__(512) void reduce_bucket(
        const unsigned* __restrict__ Sb,
        const int2* __restrict__ recs,
        const int* __restrict__ boffs,
        const float* __restrict__ bias,
        float* __restrict__ out) {
    __shared__ __align__(16) float acc[128 * APAD];   // 67584 B

    const int t    = threadIdx.x;
    const int c    = blockIdx.x;
    const int lane = t & 63;
    const int wave = t >> 6;
    const int qr   = lane >> 4;    // which record of the group of 4
    const int ql   = lane & 15;    // feat octet: feats 8ql..8ql+7

    for (int i = t; i < 128 * APAD; i += 512) acc[i] = 0.f;
    __syncthreads();

    const int beg = boffs[c];
    const int end = boffs[c + 1];
    const int cnt = end - beg;
    const int per = (cnt + 7) >> 3;          // records per wave
    const int wbeg = beg + wave * per;
    const int wend = min(wbeg + per, end);

    for (int base = wbeg; base < wend; base += 64) {
        int2 rec = make_int2(0, 0);
        if (base + lane < wend) rec = recs[base + lane];
        const int m  = min(64, wend - base);
        const int ng = (m + 3) >> 2;         // groups of 4 records

        int g = 0;
        for (; g + 4 <= ng; g += 4) {
            int idx0 = (g + 0) * 4 + qr, idx1 = (g + 1) * 4 + qr;
            int idx2 = (g + 2) * 4 + qr, idx3 = (g + 3) * 4 + qr;
            int sx0 = __shfl(rec.x, idx0); int sx1 = __shfl(rec.x, idx1);
            int sx2 = __shfl(rec.x, idx2); int sx3 = __shfl(rec.x, idx3);
            float v0 = __int_as_float(__shfl(rec.y, idx0));
            float v1 = __int_as_float(__shfl(rec.y, idx1));
            float v2 = __int_as_float(__shfl(rec.y, idx2));
            float v3 = __int_as_float(__shfl(rec.y, idx3));
            uint4 p0 = ((const uint4*)(Sb + (size_t)(sx0 & 0x1FFFF) * 64))[ql];
            uint4 p1 = ((const uint4*)(Sb + (size_t)(sx1 & 0x1FFFF) * 64))[ql];
            uint4 p2 = ((const uint4*)(Sb + (size_t)(sx2 & 0x1FFFF) * 64))[ql];
            uint4 p3 = ((const uint4*)(Sb + (size_t)(sx3 & 0x1FFFF) * 64))[ql];
            ACC8(sx0, v0, p0);
            ACC8(sx1, v1, p1);
            ACC8(sx2, v2, p2);
            ACC8(sx3, v3, p3);
        }
        for (; g < ng; ++g) {
            int idx0 = g * 4 + qr;
            int sx0 = __shfl(rec.x, idx0);
            float v0 = __int_as_float(__shfl(rec.y, idx0));
            uint4 p0 = ((const uint4*)(Sb + (size_t)(sx0 & 0x1FFFF) * 64))[ql];
            ACC8(sx0, v0, p0);
        }
    }
    __syncthreads();

    // writeout: coalesced float4 stores, bias fused
    for (int i = t; i < 128 * 32; i += 512) {
        int row = i >> 5, q = i & 31;
        int node = c * 128 + row;
        if (node < N_NODES) {
            const float* ap = acc + row * APAD + q * 4;
            float4 b4 = ((const float4*)bias)[q];
            float4 r = make_float4(ap[0] + b4.x, ap[1] + b4.y,
                                   ap[2] + b4.z, ap[3] + b4.w);
            ((float4*)(out + (size_t)node * D))[q] = r;
        }
    }
}

extern "C" void kernel_launch(void* const* d_in, const int* in_sizes, int n_in,
                              void* d_out, int out_size, void* d_ws, size_t ws_size,
                              hipStream_t stream) {
    const float* X    = (const float*)d_in[0];
    const int*   esrc = (const int*)  d_in[1];
    const int*   edst = (const int*)  d_in[2];
    const float* eval = (const float*)d_in[3];
    const float* W    = (const float*)d_in[4];
    const float* bias = (const float*)d_in[5];
    float* out = (float*)d_out;

    char* ws = (char*)d_ws;
    unsigned* SbU   = (unsigned*)(ws + OFF_SB);
    int2*     recs  = (int2*)    (ws + OFF_REC);
    int*      ghist = (int*)     (ws + OFF_GHIST);
    int*      boffs = (int*)     (ws + OFF_BOFFS);
    int*      gcur  = (int*)     (ws + OFF_GCUR);

    // S = X @ W (bf16, MFMA)
    gemm_mfma<<<782, 256, 0, stream>>>(X, W, SbU);

    // Coarse counting sort of edges by dst bucket (128 nodes per bucket)
    hipMemsetAsync(ghist, 0, K1C * 4, stream);
    hist_coarse<<<256, 256, 0, stream>>>(edst, ghist);
    scan_coarse<<<1, 256, 0, stream>>>(ghist, boffs, gcur);
    partition_edges<<<NCHUNK, 512, 0, stream>>>(esrc, edst, eval, gcur, recs);

    // Bucket-level gather + LDS accumulate: out[n] = bias + sum val * S[src]
    reduce_bucket<<<K1C, 512, 0, stream>>>(SbU, recs, boffs, bias, out);
}

// Round 3
// 377.548 us; speedup vs baseline: 7.7063x; 7.7063x over previous
//
#include <hip/hip_runtime.h>

#define N_NODES 100000
#define N_EDGES 3200000
#define D 128

#define K1C    782        // coarse buckets: bucket = dst >> 7 (128 nodes each)
#define CHUNK  6144       // edges per partition block
#define NCHUNK 521        // ceil(N_EDGES / CHUNK)
#define CAP    5120       // max records per bucket staged in LDS (mean 4096, 16 sigma)

// ---------------------------------------------------------------------------
// Workspace layout (bytes). Total ~77.3 MB; ws >= 78,000,512 proven round 2.
// ---------------------------------------------------------------------------
static const size_t OFF_SB    = 0;           // S bf16 packed: N*64 uints = 25.6 MB
static const size_t OFF_REC   = 25600000;    // E int2 (coarse-partitioned)
static const size_t OFF_GHIST = 77200000;
static const size_t OFF_BOFFS = 77204096;
static const size_t OFF_GCUR  = 77208192;

typedef __attribute__((ext_vector_type(8))) short bf16x8;
typedef __attribute__((ext_vector_type(4))) float f32x4;

__device__ __forceinline__ unsigned short f2bf(float f) {
    unsigned u = __float_as_uint(f);
    return (unsigned short)((u + 0x7FFFu + ((u >> 16) & 1u)) >> 16);   // RNE
}

// ---------------------------------------------------------------------------
// S = X @ W via MFMA — verified (absmax matched VALU-bf16 path).
// ---------------------------------------------------------------------------
__global__ __launch_bounds__(256) void gemm_mfma(const float* __restrict__ X,
                                                 const float* __restrict__ W,
                                                 unsigned* __restrict__ Sb) {
    __shared__ __align__(16) union {
        unsigned short wfrag[8][4][64][8];  // [ct][kt][lane][j] = 32 KB
        unsigned       stage[4][32][68];    // [wave][row][dword] = 34 KB
    } u;

    const int t    = threadIdx.x;
    const int lane = t & 63;
    const int wave = t >> 6;
    const int quad = lane >> 4;
    const int li   = lane & 15;
    const int rowBase = blockIdx.x * 128;

    // stage W[k][n] fp32 -> pre-packed bf16 B-fragments
    for (int i = t; i < D * D; i += 256) {
        int k = i >> 7, n = i & 127;
        u.wfrag[n >> 4][k >> 5][((k >> 3) & 3) * 16 + (n & 15)][k & 7] = f2bf(W[i]);
    }
    __syncthreads();

    f32x4 acc[2][8];
#pragma unroll
    for (int rt = 0; rt < 2; ++rt)
#pragma unroll
        for (int ct = 0; ct < 8; ++ct)
            acc[rt][ct] = (f32x4){0.f, 0.f, 0.f, 0.f};

#pragma unroll
    for (int kt = 0; kt < 4; ++kt) {
        bf16x8 a[2];
#pragma unroll
        for (int rt = 0; rt < 2; ++rt) {
            int row = rowBase + wave * 32 + rt * 16 + li;
            if (row >= N_NODES) row = N_NODES - 1;           // clamp; store masked
            const float* xp = X + (size_t)row * D + kt * 32 + quad * 8;
            float4 f0 = ((const float4*)xp)[0];
            float4 f1 = ((const float4*)xp)[1];
            bf16x8 av;
            av[0] = (short)f2bf(f0.x); av[1] = (short)f2bf(f0.y);
            av[2] = (short)f2bf(f0.z); av[3] = (short)f2bf(f0.w);
            av[4] = (short)f2bf(f1.x); av[5] = (short)f2bf(f1.y);
            av[6] = (short)f2bf(f1.z); av[7] = (short)f2bf(f1.w);
            a[rt] = av;
        }
#pragma unroll
        for (int ct = 0; ct < 8; ++ct) {
            bf16x8 b = *(const bf16x8*)&u.wfrag[ct][kt][lane][0];
            acc[0][ct] = __builtin_amdgcn_mfma_f32_16x16x32_bf16(a[0], b, acc[0][ct], 0, 0, 0);
            acc[1][ct] = __builtin_amdgcn_mfma_f32_16x16x32_bf16(a[1], b, acc[1][ct], 0, 0, 0);
        }
    }
    __syncthreads();

    unsigned short* sw = (unsigned short*)&u.stage[wave][0][0];  // 32 x 136 bf16
#pragma unroll
    for (int rt = 0; rt < 2; ++rt)
#pragma unroll
        for (int r = 0; r < 4; ++r) {
            int lrow = rt * 16 + quad * 4 + r;
#pragma unroll
            for (int ct = 0; ct < 8; ++ct)
                sw[lrow * 136 + ct * 16 + li] = f2bf(acc[rt][ct][r]);
        }
    for (int lrow = 0; lrow < 32; ++lrow) {
        int node = rowBase + wave * 32 + lrow;
        if (node < N_NODES)
            Sb[(size_t)node * 64 + lane] = ((unsigned*)sw)[lrow * 68 + lane];
    }
}

// ---------------------------------------------------------------------------
// Coarse histogram over K1C buckets (bucket = dst >> 7)
// ---------------------------------------------------------------------------
__global__ __launch_bounds__(256) void hist_coarse(const int* __restrict__ edst,
                                                   int* __restrict__ ghist) {
    __shared__ int h[K1C];
    for (int i = threadIdx.x; i < K1C; i += 256) h[i] = 0;
    __syncthreads();
    for (int e = blockIdx.x * 256 + threadIdx.x; e < N_EDGES; e += gridDim.x * 256)
        atomicAdd(&h[edst[e] >> 7], 1);
    __syncthreads();
    for (int i = threadIdx.x; i < K1C; i += 256)
        if (h[i]) atomicAdd(&ghist[i], h[i]);
}

__global__ __launch_bounds__(256) void scan_coarse(const int* __restrict__ ghist,
                                                   int* __restrict__ boffs,
                                                   int* __restrict__ gcursor) {
    __shared__ int sc[256];
    const int t = threadIdx.x;
    int v[4]; int s = 0;
#pragma unroll
    for (int j = 0; j < 4; ++j) {
        int idx = t * 4 + j;
        v[j] = (idx < K1C) ? ghist[idx] : 0;
        s += v[j];
    }
    sc[t] = s;
    __syncthreads();
    for (int off = 1; off < 256; off <<= 1) {
        int u = (t >= off) ? sc[t - off] : 0;
        __syncthreads();
        sc[t] += u;
        __syncthreads();
    }
    int run = (t == 0) ? 0 : sc[t - 1];
#pragma unroll
    for (int j = 0; j < 4; ++j) {
        int idx = t * 4 + j;
        if (idx < K1C) { boffs[idx] = run; gcursor[idx] = run; }
        run += v[j];
    }
    if (t == 255) boffs[K1C] = run;
}

// ---------------------------------------------------------------------------
// LDS-staged coarse partition, two-pass-per-block (hist then re-read+scatter).
// rec.x = src | (dst&127)<<17 ; rec.y = val bits.  Int LDS atomics only.
// ---------------------------------------------------------------------------
__global__ __launch_bounds__(512) void partition_edges(
        const int* __restrict__ esrc,
        const int* __restrict__ edst,
        const float* __restrict__ eval,
        int* __restrict__ gcursor,
        int2* __restrict__ rec_out) {
    __shared__ int  hist[K1C];
    __shared__ int  lofs[K1C];
    __shared__ int  gbase[K1C];
    __shared__ int  cur[K1C];
    __shared__ int  sc[512];
    __shared__ int2 staged[CHUNK];
    __shared__ unsigned short bkt[CHUNK];

    const int t   = threadIdx.x;
    const int e0  = blockIdx.x * CHUNK;
    const int cnt = min(CHUNK, N_EDGES - e0);

    for (int i = t; i < K1C; i += 512) hist[i] = 0;
    __syncthreads();

    // pass 1: block-local histogram (edst read is coalesced; re-read below is L2-hot)
    for (int i = t; i < cnt; i += 512)
        atomicAdd(&hist[edst[e0 + i] >> 7], 1);
    __syncthreads();

    // block scan: two buckets per thread (K1C=782 <= 1024)
    int i0 = t * 2, i1 = t * 2 + 1;
    int hv0 = (i0 < K1C) ? hist[i0] : 0;
    int hv1 = (i1 < K1C) ? hist[i1] : 0;
    sc[t] = hv0 + hv1;
    __syncthreads();
    for (int off = 1; off < 512; off <<= 1) {
        int u = (t >= off) ? sc[t - off] : 0;
        __syncthreads();
        sc[t] += u;
        __syncthreads();
    }
    {
        int excl = sc[t] - (hv0 + hv1);
        if (i0 < K1C) {
            lofs[i0]  = excl;
            cur[i0]   = excl;
            gbase[i0] = hv0 ? atomicAdd(&gcursor[i0], hv0) : 0;
        }
        if (i1 < K1C) {
            lofs[i1]  = excl + hv0;
            cur[i1]   = excl + hv0;
            gbase[i1] = hv1 ? atomicAdd(&gcursor[i1], hv1) : 0;
        }
    }
    __syncthreads();

    // pass 2: re-read edges, scatter into LDS staging (bucket-sorted)
    for (int i = t; i < cnt; i += 512) {
        int e = e0 + i;
        int d = edst[e];
        int b = d >> 7;
        int pos = atomicAdd(&cur[b], 1);
        staged[pos] = make_int2(esrc[e] | ((d & 127) << 17), __float_as_int(eval[e]));
        bkt[pos] = (unsigned short)b;
    }
    __syncthreads();

    // writeout: contiguous per-bucket runs
    for (int i = t; i < cnt; i += 512) {
        int bb = bkt[i];
        rec_out[gbase[bb] + (i - lofs[bb])] = staged[i];
    }
}

// ---------------------------------------------------------------------------
// Merged fine-sort + segmented reduce. One block per 128-node dst bucket:
//  1) bucket's records (avg 4096, 16-sigma max < CAP) counting-sorted into
//     LDS by dst-local (int LDS atomics — cheap; NO float LDS atomics),
//  2) per-node register reduce: wave w owns nodes 16w..16w+15. Half-wave
//     record pairing (lanes 0-31 = even record, 32-63 = odd); records come
//     from LDS broadcast ds_read_b64 (uniform addr per half) — no shfls.
//     4 pairs unrolled -> 8 outstanding 256 B gathers per wave.
// Replaces the old fine_sort kernel: saves 51.2 MB global RW + a launch.
// ---------------------------------------------------------------------------
#define FMA4(q, p) {                                                         \
    float v = __int_as_float((q).y);                                         \
    a0 += v * __uint_as_float((p).x << 16);                                  \
    a1 += v * __uint_as_float((p).x & 0xFFFF0000u);                          \
    a2 += v * __uint_as_float((p).y << 16);                                  \
    a3 += v * __uint_as_float((p).y & 0xFFFF0000u);                          \
}

__global__ __launch_bounds__(512) void sort_reduce(
        const unsigned* __restrict__ Sb,
        const int2* __restrict__ recs,
        const int* __restrict__ boffs,
        const float* __restrict__ bias,
        float* __restrict__ out) {
    __shared__ __align__(16) int2 staged[CAP];     // 40 KB
    __shared__ int h[128];
    __shared__ int cur[128];
    __shared__ int offs_l[129];
    __shared__ int sc[128];

    const int t    = threadIdx.x;
    const int c    = blockIdx.x;
    const int lane = t & 63;
    const int wave = t >> 6;
    const int half = lane >> 5;        // which record of the pair
    const int hl   = lane & 31;        // lane within half: feats 4hl..4hl+3

    const int beg = boffs[c];
    const int cnt = min(boffs[c + 1] - beg, CAP);

    if (t < 128) h[t] = 0;
    __syncthreads();

    // pass 1: dst-local histogram
    for (int i = t; i < cnt; i += 512)
        atomicAdd(&h[(recs[beg + i].x >> 17) & 127], 1);
    __syncthreads();

    // scan 128 entries
    if (t < 128) sc[t] = h[t];
    __syncthreads();
    for (int off = 1; off < 128; off <<= 1) {
        int u = 0;
        if (t < 128 && t >= off) u = sc[t - off];
        __syncthreads();
        if (t < 128) sc[t] += u;
        __syncthreads();
    }
    if (t < 128) {
        int excl = sc[t] - h[t];
        offs_l[t] = excl;
        cur[t]    = excl;
    }
    if (t == 0) offs_l[128] = cnt;
    __syncthreads();

    // pass 2: scatter into LDS, sorted by dst-local (re-read is L2-hot)
    for (int i = t; i < cnt; i += 512) {
        int2 q = recs[beg + i];
        int dl = (q.x >> 17) & 127;
        staged[atomicAdd(&cur[dl], 1)] = q;
    }
    __syncthreads();

    // per-node register reduce
    for (int nl = wave * 16; nl < wave * 16 + 16; ++nl) {
        const int node = c * 128 + nl;
        const int sbeg = offs_l[nl];
        const int send = offs_l[nl + 1];

        float a0 = 0.f, a1 = 0.f, a2 = 0.f, a3 = 0.f;

        int r = sbeg + half;
        for (; r + 6 < send; r += 8) {
            int2 q0 = staged[r];
            int2 q1 = staged[r + 2];
            int2 q2 = staged[r + 4];
            int2 q3 = staged[r + 6];
            uint2 p0 = ((const uint2*)(Sb + (size_t)(q0.x & 0x1FFFF) * 64))[hl];
            uint2 p1 = ((const uint2*)(Sb + (size_t)(q1.x & 0x1FFFF) * 64))[hl];
            uint2 p2 = ((const uint2*)(Sb + (size_t)(q2.x & 0x1FFFF) * 64))[hl];
            uint2 p3 = ((const uint2*)(Sb + (size_t)(q3.x & 0x1FFFF) * 64))[hl];
            FMA4(q0, p0);
            FMA4(q1, p1);
            FMA4(q2, p2);
            FMA4(q3, p3);
        }
        for (; r < send; r += 2) {
            int2 q0 = staged[r];
            uint2 p0 = ((const uint2*)(Sb + (size_t)(q0.x & 0x1FFFF) * 64))[hl];
            FMA4(q0, p0);
        }

        // combine the two halves (feats 4hl..4hl+3 live in lanes hl and hl+32)
        a0 += __shfl(a0, lane ^ 32);
        a1 += __shfl(a1, lane ^ 32);
        a2 += __shfl(a2, lane ^ 32);
        a3 += __shfl(a3, lane ^ 32);

        if (half == 0 && node < N_NODES) {
            float4 b4 = ((const float4*)bias)[hl];
            float4 r4 = make_float4(a0 + b4.x, a1 + b4.y, a2 + b4.z, a3 + b4.w);
            ((float4*)(out + (size_t)node * D))[hl] = r4;
        }
    }
}

extern "C" void kernel_launch(void* const* d_in, const int* in_sizes, int n_in,
                              void* d_out, int out_size, void* d_ws, size_t ws_size,
                              hipStream_t stream) {
    const float* X    = (const float*)d_in[0];
    const int*   esrc = (const int*)  d_in[1];
    const int*   edst = (const int*)  d_in[2];
    const float* eval = (const float*)d_in[3];
    const float* W    = (const float*)d_in[4];
    const float* bias = (const float*)d_in[5];
    float* out = (float*)d_out;

    char* ws = (char*)d_ws;
    unsigned* SbU   = (unsigned*)(ws + OFF_SB);
    int2*     recs  = (int2*)    (ws + OFF_REC);
    int*      ghist = (int*)     (ws + OFF_GHIST);
    int*      boffs = (int*)     (ws + OFF_BOFFS);
    int*      gcur  = (int*)     (ws + OFF_GCUR);

    // S = X @ W (bf16, MFMA)
    gemm_mfma<<<782, 256, 0, stream>>>(X, W, SbU);

    // Coarse counting sort of edges by dst bucket (128 nodes per bucket)
    hipMemsetAsync(ghist, 0, K1C * 4, stream);
    hist_coarse<<<256, 256, 0, stream>>>(edst, ghist);
    scan_coarse<<<1, 256, 0, stream>>>(ghist, boffs, gcur);
    partition_edges<<<NCHUNK, 512, 0, stream>>>(esrc, edst, eval, gcur, recs);

    // Merged in-LDS fine sort + segmented reduce:
    // out[n] = bias + sum val * S[src]
    sort_reduce<<<K1C, 512, 0, stream>>>(SbU, recs, boffs, bias, out);
}

// Round 4
// 362.253 us; speedup vs baseline: 8.0317x; 1.0422x over previous
//
#include <hip/hip_runtime.h>

#define N_NODES 100000
#define N_EDGES 3200000
#define D 128

#define K1C    391        // coarse buckets: bucket = dst >> 8 (256 nodes each)
#define CHUNK  6144       // edges per partition block
#define NCHUNK 521        // ceil(N_EDGES / CHUNK)

// ---------------------------------------------------------------------------
// Workspace layout (bytes). Total ~77.3 MB; ws >= 78,000,512 proven round 2.
// ---------------------------------------------------------------------------
static const size_t OFF_SB    = 0;           // S bf16 packed: N*64 uints = 25.6 MB
static const size_t OFF_REC   = 25600000;    // E int2 (coarse-partitioned)
static const size_t OFF_SORT2 = 51200000;    // E int2 (fine-sorted)
static const size_t OFF_OFFS  = 76800000;    // N ints
static const size_t OFF_GHIST = 77200000;
static const size_t OFF_BOFFS = 77204096;
static const size_t OFF_GCUR  = 77208192;

typedef __attribute__((ext_vector_type(8))) short bf16x8;
typedef __attribute__((ext_vector_type(4))) float f32x4;

__device__ __forceinline__ unsigned short f2bf(float f) {
    unsigned u = __float_as_uint(f);
    return (unsigned short)((u + 0x7FFFu + ((u >> 16) & 1u)) >> 16);   // RNE
}

// ---------------------------------------------------------------------------
// S = X @ W via MFMA — verified (absmax matched VALU-bf16 path).
// ---------------------------------------------------------------------------
__global__ __launch_bounds__(256) void gemm_mfma(const float* __restrict__ X,
                                                 const float* __restrict__ W,
                                                 unsigned* __restrict__ Sb) {
    __shared__ __align__(16) union {
        unsigned short wfrag[8][4][64][8];  // [ct][kt][lane][j] = 32 KB
        unsigned       stage[4][32][68];    // [wave][row][dword] = 34 KB
    } u;

    const int t    = threadIdx.x;
    const int lane = t & 63;
    const int wave = t >> 6;
    const int quad = lane >> 4;
    const int li   = lane & 15;
    const int rowBase = blockIdx.x * 128;

    // stage W[k][n] fp32 -> pre-packed bf16 B-fragments
    for (int i = t; i < D * D; i += 256) {
        int k = i >> 7, n = i & 127;
        u.wfrag[n >> 4][k >> 5][((k >> 3) & 3) * 16 + (n & 15)][k & 7] = f2bf(W[i]);
    }
    __syncthreads();

    f32x4 acc[2][8];
#pragma unroll
    for (int rt = 0; rt < 2; ++rt)
#pragma unroll
        for (int ct = 0; ct < 8; ++ct)
            acc[rt][ct] = (f32x4){0.f, 0.f, 0.f, 0.f};

#pragma unroll
    for (int kt = 0; kt < 4; ++kt) {
        bf16x8 a[2];
#pragma unroll
        for (int rt = 0; rt < 2; ++rt) {
            int row = rowBase + wave * 32 + rt * 16 + li;
            if (row >= N_NODES) row = N_NODES - 1;           // clamp; store masked
            const float* xp = X + (size_t)row * D + kt * 32 + quad * 8;
            float4 f0 = ((const float4*)xp)[0];
            float4 f1 = ((const float4*)xp)[1];
            bf16x8 av;
            av[0] = (short)f2bf(f0.x); av[1] = (short)f2bf(f0.y);
            av[2] = (short)f2bf(f0.z); av[3] = (short)f2bf(f0.w);
            av[4] = (short)f2bf(f1.x); av[5] = (short)f2bf(f1.y);
            av[6] = (short)f2bf(f1.z); av[7] = (short)f2bf(f1.w);
            a[rt] = av;
        }
#pragma unroll
        for (int ct = 0; ct < 8; ++ct) {
            bf16x8 b = *(const bf16x8*)&u.wfrag[ct][kt][lane][0];
            acc[0][ct] = __builtin_amdgcn_mfma_f32_16x16x32_bf16(a[0], b, acc[0][ct], 0, 0, 0);
            acc[1][ct] = __builtin_amdgcn_mfma_f32_16x16x32_bf16(a[1], b, acc[1][ct], 0, 0, 0);
        }
    }
    __syncthreads();

    unsigned short* sw = (unsigned short*)&u.stage[wave][0][0];  // 32 x 136 bf16
#pragma unroll
    for (int rt = 0; rt < 2; ++rt)
#pragma unroll
        for (int r = 0; r < 4; ++r) {
            int lrow = rt * 16 + quad * 4 + r;
#pragma unroll
            for (int ct = 0; ct < 8; ++ct)
                sw[lrow * 136 + ct * 16 + li] = f2bf(acc[rt][ct][r]);
        }
    for (int lrow = 0; lrow < 32; ++lrow) {
        int node = rowBase + wave * 32 + lrow;
        if (node < N_NODES)
            Sb[(size_t)node * 64 + lane] = ((unsigned*)sw)[lrow * 68 + lane];
    }
}

// ---------------------------------------------------------------------------
// Coarse histogram over K1C buckets (bucket = dst >> 8)
// ---------------------------------------------------------------------------
__global__ __launch_bounds__(256) void hist_coarse(const int* __restrict__ edst,
                                                   int* __restrict__ ghist) {
    __shared__ int h[K1C];
    for (int i = threadIdx.x; i < K1C; i += 256) h[i] = 0;
    __syncthreads();
    for (int e = blockIdx.x * 256 + threadIdx.x; e < N_EDGES; e += gridDim.x * 256)
        atomicAdd(&h[edst[e] >> 8], 1);
    __syncthreads();
    for (int i = threadIdx.x; i < K1C; i += 256)
        if (h[i]) atomicAdd(&ghist[i], h[i]);
}

__global__ __launch_bounds__(256) void scan_coarse(const int* __restrict__ ghist,
                                                   int* __restrict__ boffs,
                                                   int* __restrict__ gcursor) {
    __shared__ int sc[256];
    const int t = threadIdx.x;
    int v[2]; int s = 0;
#pragma unroll
    for (int j = 0; j < 2; ++j) {
        int idx = t * 2 + j;
        v[j] = (idx < K1C) ? ghist[idx] : 0;
        s += v[j];
    }
    sc[t] = s;
    __syncthreads();
    for (int off = 1; off < 256; off <<= 1) {
        int u = (t >= off) ? sc[t - off] : 0;
        __syncthreads();
        sc[t] += u;
        __syncthreads();
    }
    int run = (t == 0) ? 0 : sc[t - 1];
#pragma unroll
    for (int j = 0; j < 2; ++j) {
        int idx = t * 2 + j;
        if (idx < K1C) { boffs[idx] = run; gcursor[idx] = run; }
        run += v[j];
    }
    if (t == 255) boffs[K1C] = run;
}

// ---------------------------------------------------------------------------
// LDS-staged coarse partition, two-pass-per-block (hist then re-read+scatter).
// rec.x = src | (dst&255)<<17 ; rec.y = val bits.  Int LDS atomics only.
// ---------------------------------------------------------------------------
__global__ __launch_bounds__(512) void partition_edges(
        const int* __restrict__ esrc,
        const int* __restrict__ edst,
        const float* __restrict__ eval,
        int* __restrict__ gcursor,
        int2* __restrict__ rec_out) {
    __shared__ int  hist[K1C];
    __shared__ int  lofs[K1C];
    __shared__ int  gbase[K1C];
    __shared__ int  cur[K1C];
    __shared__ int  sc[512];
    __shared__ int2 staged[CHUNK];
    __shared__ unsigned short bkt[CHUNK];

    const int t   = threadIdx.x;
    const int e0  = blockIdx.x * CHUNK;
    const int cnt = min(CHUNK, N_EDGES - e0);

    for (int i = t; i < K1C; i += 512) hist[i] = 0;
    __syncthreads();

    // pass 1: block-local histogram (edst read is coalesced; re-read below is L2-hot)
    for (int i = t; i < cnt; i += 512)
        atomicAdd(&hist[edst[e0 + i] >> 8], 1);
    __syncthreads();

    // block scan: one bucket per thread (K1C=391 <= 512)
    int hv = (t < K1C) ? hist[t] : 0;
    sc[t] = hv;
    __syncthreads();
    for (int off = 1; off < 512; off <<= 1) {
        int u = (t >= off) ? sc[t - off] : 0;
        __syncthreads();
        sc[t] += u;
        __syncthreads();
    }
    if (t < K1C) {
        int excl = sc[t] - hv;
        lofs[t]  = excl;
        cur[t]   = excl;
        gbase[t] = hv ? atomicAdd(&gcursor[t], hv) : 0;
    }
    __syncthreads();

    // pass 2: re-read edges, scatter into LDS staging (bucket-sorted)
    for (int i = t; i < cnt; i += 512) {
        int e = e0 + i;
        int d = edst[e];
        int b = d >> 8;
        int pos = atomicAdd(&cur[b], 1);
        staged[pos] = make_int2(esrc[e] | ((d & 255) << 17), __float_as_int(eval[e]));
        bkt[pos] = (unsigned short)b;
    }
    __syncthreads();

    // writeout: contiguous per-bucket runs (~126 B each)
    for (int i = t; i < cnt; i += 512) {
        int bb = bkt[i];
        rec_out[gbase[bb] + (i - lofs[bb])] = staged[i];
    }
}

// ---------------------------------------------------------------------------
// Fine sort within each 256-node coarse bucket. Scatter window ~65 KB ->
// L2-resident. Emits per-node segment offsets. One node per thread.
// ---------------------------------------------------------------------------
__global__ __launch_bounds__(256) void fine_sort(
        const int2* __restrict__ rec,
        const int* __restrict__ boffs,
        int* __restrict__ offs,
        int2* __restrict__ sorted2) {
    __shared__ int h[256];
    __shared__ int cur[256];
    __shared__ int sc[256];

    const int c   = blockIdx.x;
    const int t   = threadIdx.x;
    const int beg = boffs[c];
    const int end = boffs[c + 1];

    h[t] = 0;
    __syncthreads();

    for (int i = beg + t; i < end; i += 256)
        atomicAdd(&h[(rec[i].x >> 17) & 255], 1);
    __syncthreads();

    sc[t] = h[t];
    __syncthreads();
    for (int off = 1; off < 256; off <<= 1) {
        int u = (t >= off) ? sc[t - off] : 0;
        __syncthreads();
        sc[t] += u;
        __syncthreads();
    }
    {
        int excl = sc[t] - h[t];
        int node = c * 256 + t;
        if (node < N_NODES) offs[node] = beg + excl;
        cur[t] = beg + excl;
    }
    __syncthreads();

    for (int i = beg + t; i < end; i += 256) {
        int2 q = rec[i];
        int dl = (q.x >> 17) & 255;
        int p = atomicAdd(&cur[dl], 1);
        sorted2[p] = make_int2(q.x & 0x1FFFF, q.y);
    }
}

// ---------------------------------------------------------------------------
// Wave-per-node segmented reduce, QUARTER-wave record parallelism:
// lane quarter qr = lane>>4 owns record 4g+qr of each group g; 16 lanes per
// quarter each load uint4 (16 B) -> one full 256 B S-row per record per
// instruction. 4 groups unrolled -> 4 outstanding dwordx4 loads = 4 KB in
// flight per wave (2x round-1), half the shfl/unpack work per byte.
// Each lane accumulates feats 8ql..8ql+7 (8 f32 accs); quarters combined
// via shfl(lane^16)+shfl(lane^32); quarter 0 stores 2x float4 with bias.
// Tail records are zero-padded (val=0, src=0) -> harmless row-0 loads.
// ---------------------------------------------------------------------------
#define FMA8(v, p) {                                                         \
    a0 += (v) * __uint_as_float((p).x << 16);                                \
    a1 += (v) * __uint_as_float((p).x & 0xFFFF0000u);                        \
    a2 += (v) * __uint_as_float((p).y << 16);                                \
    a3 += (v) * __uint_as_float((p).y & 0xFFFF0000u);                        \
    a4 += (v) * __uint_as_float((p).z << 16);                                \
    a5 += (v) * __uint_as_float((p).z & 0xFFFF0000u);                        \
    a6 += (v) * __uint_as_float((p).w << 16);                                \
    a7 += (v) * __uint_as_float((p).w & 0xFFFF0000u);                        \
}

__global__ __launch_bounds__(256) void reduce_segments(
        const unsigned* __restrict__ Sb,
        const int2* __restrict__ sorted,
        const int* __restrict__ offs,
        const float* __restrict__ bias,
        float* __restrict__ out) {
    const int lane = threadIdx.x & 63;
    const int node = (blockIdx.x * 256 + threadIdx.x) >> 6;
    if (node >= N_NODES) return;

    const int qr = lane >> 4;        // which record of the group of 4
    const int ql = lane & 15;        // lane within quarter: feats 8ql..8ql+7

    const int beg = offs[node];
    const int end = (node == N_NODES - 1) ? N_EDGES : offs[node + 1];

    float a0 = 0.f, a1 = 0.f, a2 = 0.f, a3 = 0.f;
    float a4 = 0.f, a5 = 0.f, a6 = 0.f, a7 = 0.f;

    for (int base = beg; base < end; base += 64) {
        const int m = min(64, end - base);
        int2 rec = make_int2(0, 0);
        if (base + lane < end) rec = sorted[base + lane];
        const int ng = (m + 3) >> 2;         // groups of 4 records

        int g = 0;
        for (; g + 4 <= ng; g += 4) {
            int i0 = 4 * (g + 0) + qr, i1 = 4 * (g + 1) + qr;
            int i2 = 4 * (g + 2) + qr, i3 = 4 * (g + 3) + qr;
            int s0 = __shfl(rec.x, i0); int s1 = __shfl(rec.x, i1);
            int s2 = __shfl(rec.x, i2); int s3 = __shfl(rec.x, i3);
            float v0 = __int_as_float(__shfl(rec.y, i0));
            float v1 = __int_as_float(__shfl(rec.y, i1));
            float v2 = __int_as_float(__shfl(rec.y, i2));
            float v3 = __int_as_float(__shfl(rec.y, i3));
            uint4 p0 = ((const uint4*)(Sb + (size_t)s0 * 64))[ql];
            uint4 p1 = ((const uint4*)(Sb + (size_t)s1 * 64))[ql];
            uint4 p2 = ((const uint4*)(Sb + (size_t)s2 * 64))[ql];
            uint4 p3 = ((const uint4*)(Sb + (size_t)s3 * 64))[ql];
            FMA8(v0, p0);
            FMA8(v1, p1);
            FMA8(v2, p2);
            FMA8(v3, p3);
        }
        for (; g < ng; ++g) {
            int i0 = 4 * g + qr;
            int s0 = __shfl(rec.x, i0);
            float v0 = __int_as_float(__shfl(rec.y, i0));
            uint4 p0 = ((const uint4*)(Sb + (size_t)s0 * 64))[ql];
            FMA8(v0, p0);
        }
    }

    // combine the four quarters (feats 8ql..8ql+7 live in lanes ql, ql+16,
    // ql+32, ql+48)
    a0 += __shfl(a0, lane ^ 16); a1 += __shfl(a1, lane ^ 16);
    a2 += __shfl(a2, lane ^ 16); a3 += __shfl(a3, lane ^ 16);
    a4 += __shfl(a4, lane ^ 16); a5 += __shfl(a5, lane ^ 16);
    a6 += __shfl(a6, lane ^ 16); a7 += __shfl(a7, lane ^ 16);
    a0 += __shfl(a0, lane ^ 32); a1 += __shfl(a1, lane ^ 32);
    a2 += __shfl(a2, lane ^ 32); a3 += __shfl(a3, lane ^ 32);
    a4 += __shfl(a4, lane ^ 32); a5 += __shfl(a5, lane ^ 32);
    a6 += __shfl(a6, lane ^ 32); a7 += __shfl(a7, lane ^ 32);

    if (qr == 0) {
        float4 b0 = ((const float4*)bias)[2 * ql];
        float4 b1 = ((const float4*)bias)[2 * ql + 1];
        float4 r0 = make_float4(a0 + b0.x, a1 + b0.y, a2 + b0.z, a3 + b0.w);
        float4 r1 = make_float4(a4 + b1.x, a5 + b1.y, a6 + b1.z, a7 + b1.w);
        ((float4*)(out + (size_t)node * D))[2 * ql]     = r0;
        ((float4*)(out + (size_t)node * D))[2 * ql + 1] = r1;
    }
}

extern "C" void kernel_launch(void* const* d_in, const int* in_sizes, int n_in,
                              void* d_out, int out_size, void* d_ws, size_t ws_size,
                              hipStream_t stream) {
    const float* X    = (const float*)d_in[0];
    const int*   esrc = (const int*)  d_in[1];
    const int*   edst = (const int*)  d_in[2];
    const float* eval = (const float*)d_in[3];
    const float* W    = (const float*)d_in[4];
    const float* bias = (const float*)d_in[5];
    float* out = (float*)d_out;

    char* ws = (char*)d_ws;
    unsigned* SbU   = (unsigned*)(ws + OFF_SB);
    int2*     recs  = (int2*)    (ws + OFF_REC);
    int2*     srt2  = (int2*)    (ws + OFF_SORT2);
    int*      offs  = (int*)     (ws + OFF_OFFS);
    int*      ghist = (int*)     (ws + OFF_GHIST);
    int*      boffs = (int*)     (ws + OFF_BOFFS);
    int*      gcur  = (int*)     (ws + OFF_GCUR);

    // S = X @ W (bf16, MFMA)
    gemm_mfma<<<782, 256, 0, stream>>>(X, W, SbU);

    // Two-level counting sort of edges by dst (all scatters L2-resident)
    hipMemsetAsync(ghist, 0, K1C * 4, stream);
    hist_coarse<<<256, 256, 0, stream>>>(edst, ghist);
    scan_coarse<<<1, 256, 0, stream>>>(ghist, boffs, gcur);
    partition_edges<<<NCHUNK, 512, 0, stream>>>(esrc, edst, eval, gcur, recs);
    fine_sort<<<K1C, 256, 0, stream>>>(recs, boffs, offs, srt2);

    // Segmented reduce: out[n] = bias + sum val * S[src]
    reduce_segments<<<(N_NODES + 3) / 4, 256, 0, stream>>>(
        SbU, srt2, offs, bias, out);
}